// Round 1
// baseline (169.804 us; speedup 1.0000x reference)
//
#include <hip/hip_runtime.h>
#include <hip/hip_bf16.h>

#define NN 256
#define FI 128
#define FO 64

typedef short s16x8 __attribute__((ext_vector_type(8)));
typedef float f32x4 __attribute__((ext_vector_type(4)));

__device__ __forceinline__ unsigned f2bf1(float x) {
  union { float f; unsigned u; } v; v.f = x;
  unsigned r = v.u + 0x7FFFu + ((v.u >> 16) & 1u);
  return r >> 16;
}
__device__ __forceinline__ unsigned pack2(float a, float b) {
  return f2bf1(a) | (f2bf1(b) << 16);
}

// one block per (b,t) graph; 256 threads = 4 waves
__global__ __launch_bounds__(256, 2) void gat_kernel(
    const float* __restrict__ h, const float* __restrict__ W,
    const float* __restrict__ a, const float* __restrict__ adj,
    float* __restrict__ out)
{
  const int bt   = blockIdx.x;
  const int tid  = threadIdx.x;
  const int lane = tid & 63;
  const int wv   = tid >> 6;
  const int m    = lane & 15;   // frag row/col-within-16
  const int q    = lane >> 4;   // quad

  const float* __restrict__ hB   = h   + (size_t)bt * NN * FI;
  float*       __restrict__ outB = out + (size_t)bt * NN * FO;

  // LDS: WhT (bf16, o-major, stride 264 for bank spread) = 33792 B
  //      union region: sWT (phase 0/1) / sAlpha (tile loop)  = 17408 B
  __shared__ __align__(16) unsigned short sWhT[64 * 264];
  __shared__ __align__(16) unsigned char  sUni[64 * 136 * 2];
  __shared__ __align__(16) float sWh1[NN], sWh2[NN];
  __shared__ __align__(16) float sWa1[FI], sWa2[FI];
  __shared__ __align__(16) float sA[2 * FO];
  unsigned short* sWT    = (unsigned short*)sUni;   // [o][k] stride 136
  unsigned short* sAlpha = (unsigned short*)sUni;   // [i_local][j] stride 264

  // ---- Phase 0: stage a and W (bf16, transposed: o-major k-contig) ----
  if (tid < 2 * FO) sA[tid] = a[tid];
  for (int idx = tid; idx < FI * FO; idx += 256) {
    int k = idx >> 6, o = idx & 63;
    sWT[o * 136 + k] = (unsigned short)f2bf1(W[idx]);
  }
  __syncthreads();

  // ---- Phase 0b: Wa1 = W@a1, Wa2 = W@a2 (fp32, for exact logits) ----
  if (tid < FI) {
    const float* wr = W + tid * FO;
    float s1 = 0.f, s2 = 0.f;
    #pragma unroll 8
    for (int o = 0; o < FO; ++o) {
      float wval = wr[o];
      s1 += wval * sA[o];
      s2 += wval * sA[FO + o];
    }
    sWa1[tid] = s1; sWa2[tid] = s2;
  }

  // ---- Phase 1: GEMM-1  Wh = h @ W  (per wave: 64 rows) ----
  {
    const int nw = wv * 64;
    f32x4 acc[4][4];
    #pragma unroll
    for (int i0 = 0; i0 < 4; ++i0)
      #pragma unroll
      for (int j0 = 0; j0 < 4; ++j0)
        acc[i0][j0] = (f32x4){0.f, 0.f, 0.f, 0.f};

    #pragma unroll
    for (int kt = 0; kt < 4; ++kt) {
      s16x8 af[4];
      #pragma unroll
      for (int mt = 0; mt < 4; ++mt) {
        int row = nw + 16 * mt + m;
        const float* p = hB + row * FI + kt * 32 + q * 8;
        float4 x0 = *(const float4*)p;
        float4 x1 = *(const float4*)(p + 4);
        union { unsigned u[4]; s16x8 v; } pk;
        pk.u[0] = pack2(x0.x, x0.y);
        pk.u[1] = pack2(x0.z, x0.w);
        pk.u[2] = pack2(x1.x, x1.y);
        pk.u[3] = pack2(x1.z, x1.w);
        af[mt] = pk.v;
      }
      #pragma unroll
      for (int nt = 0; nt < 4; ++nt) {
        s16x8 bf = *(const s16x8*)&sWT[(16 * nt + m) * 136 + kt * 32 + q * 8];
        #pragma unroll
        for (int mt = 0; mt < 4; ++mt)
          acc[mt][nt] = __builtin_amdgcn_mfma_f32_16x16x32_bf16(af[mt], bf, acc[mt][nt], 0, 0, 0);
      }
    }
    // write Wh transposed (bf16) to LDS: C-layout row=(q*4+r), col=m
    #pragma unroll
    for (int mt = 0; mt < 4; ++mt) {
      int row0 = nw + 16 * mt + 4 * q;
      #pragma unroll
      for (int nt = 0; nt < 4; ++nt) {
        int col = 16 * nt + m;
        uint2 w;
        w.x = pack2(acc[mt][nt][0], acc[mt][nt][1]);
        w.y = pack2(acc[mt][nt][2], acc[mt][nt][3]);
        *(uint2*)&sWhT[col * 264 + row0] = w;
      }
    }
  }
  __syncthreads();

  // ---- Phase 2: Wh1/Wh2 in fp32 from global h (thread = row, L2-hot) ----
  {
    const float* hr = hB + tid * FI;
    float s1 = 0.f, s2 = 0.f;
    #pragma unroll 8
    for (int k = 0; k < FI; k += 4) {
      float4 hv = *(const float4*)(hr + k);
      float4 w1 = *(const float4*)&sWa1[k];
      float4 w2 = *(const float4*)&sWa2[k];
      s1 += hv.x * w1.x + hv.y * w1.y + hv.z * w1.z + hv.w * w1.w;
      s2 += hv.x * w2.x + hv.y * w2.y + hv.z * w2.z + hv.w * w2.w;
    }
    sWh1[tid] = s1; sWh2[tid] = s2;
  }

  // ---- Hoist B2 fragments (Wh as B operand) into registers: 16 frags ----
  const int mt2 = wv & 1;     // row-half of 32-row tile
  const int nh2 = wv >> 1;    // col-half (32 cols)
  s16x8 B2[8][2];
  #pragma unroll
  for (int kt = 0; kt < 8; ++kt)
    #pragma unroll
    for (int nn2 = 0; nn2 < 2; ++nn2) {
      int o = 16 * (2 * nh2 + nn2) + m;
      B2[kt][nn2] = *(const s16x8*)&sWhT[o * 264 + kt * 32 + q * 8];
    }
  __syncthreads();

  const float4 w2v = *(const float4*)&sWh2[4 * lane];  // this lane's 4 j-columns

  // ---- Tile loop: 8 tiles of 32 attention rows ----
  for (int it = 0; it < 8; ++it) {
    // softmax: 8 rows per wave, lane owns j = 4*lane .. 4*lane+3
    for (int rr = 0; rr < 8; ++rr) {
      int il = wv * 8 + rr;
      int i  = it * 32 + il;
      float w1 = sWh1[i];
      float4 ad = *(const float4*)&adj[i * NN + 4 * lane];
      float l0 = w1 + w2v.x; l0 = fmaxf(l0, 0.01f * l0);
      float l1 = w1 + w2v.y; l1 = fmaxf(l1, 0.01f * l1);
      float l2 = w1 + w2v.z; l2 = fmaxf(l2, 0.01f * l2);
      float l3 = w1 + w2v.w; l3 = fmaxf(l3, 0.01f * l3);
      float m0 = ad.x > 0.f ? l0 : -3.0e38f;
      float m1 = ad.y > 0.f ? l1 : -3.0e38f;
      float m2 = ad.z > 0.f ? l2 : -3.0e38f;
      float m3 = ad.w > 0.f ? l3 : -3.0e38f;
      float mx = fmaxf(fmaxf(m0, m1), fmaxf(m2, m3));
      #pragma unroll
      for (int off = 32; off > 0; off >>= 1) mx = fmaxf(mx, __shfl_xor(mx, off));
      float p0 = ad.x > 0.f ? __expf(l0 - mx) : 0.f;
      float p1 = ad.y > 0.f ? __expf(l1 - mx) : 0.f;
      float p2 = ad.z > 0.f ? __expf(l2 - mx) : 0.f;
      float p3 = ad.w > 0.f ? __expf(l3 - mx) : 0.f;
      float sm = (p0 + p1) + (p2 + p3);
      #pragma unroll
      for (int off = 32; off > 0; off >>= 1) sm += __shfl_xor(sm, off);
      float inv = 1.0f / sm;
      uint2 wr;
      wr.x = pack2(p0 * inv, p1 * inv);
      wr.y = pack2(p2 * inv, p3 * inv);
      *(uint2*)&sAlpha[il * 264 + 4 * lane] = wr;
    }
    __syncthreads();

    // GEMM-2: h_prime tile = alpha_tile @ Wh (B2 from registers)
    f32x4 acc0 = (f32x4){0.f, 0.f, 0.f, 0.f};
    f32x4 acc1 = (f32x4){0.f, 0.f, 0.f, 0.f};
    #pragma unroll
    for (int kt = 0; kt < 8; ++kt) {
      s16x8 af = *(const s16x8*)&sAlpha[(16 * mt2 + m) * 264 + kt * 32 + q * 8];
      acc0 = __builtin_amdgcn_mfma_f32_16x16x32_bf16(af, B2[kt][0], acc0, 0, 0, 0);
      acc1 = __builtin_amdgcn_mfma_f32_16x16x32_bf16(af, B2[kt][1], acc1, 0, 0, 0);
    }
    // epilogue: elu + store
    #pragma unroll
    for (int nn2 = 0; nn2 < 2; ++nn2) {
      f32x4 accv = nn2 ? acc1 : acc0;
      int col = 16 * (2 * nh2 + nn2) + m;
      #pragma unroll
      for (int r = 0; r < 4; ++r) {
        int i = it * 32 + 16 * mt2 + 4 * q + r;
        float v = accv[r];
        v = v > 0.f ? v : (__expf(v) - 1.f);
        outB[i * FO + col] = v;
      }
    }
    __syncthreads();
  }
}

extern "C" void kernel_launch(void* const* d_in, const int* in_sizes, int n_in,
                              void* d_out, int out_size, void* d_ws, size_t ws_size,
                              hipStream_t stream) {
  const float* h   = (const float*)d_in[0];
  const float* W   = (const float*)d_in[1];
  const float* a   = (const float*)d_in[2];
  const float* adj = (const float*)d_in[3];
  float* out = (float*)d_out;
  gat_kernel<<<dim3(512), dim3(256), 0, stream>>>(h, W, a, adj, out);
}